// Round 3
// baseline (831.061 us; speedup 1.0000x reference)
//
#include <hip/hip_runtime.h>

#define H 256

typedef short bf16x8 __attribute__((ext_vector_type(8)));
typedef float f32x4  __attribute__((ext_vector_type(4)));

__device__ __forceinline__ unsigned int f2bf(float f) {
    unsigned int u = __float_as_uint(f);
    return (u + 0x7fffu + ((u >> 16) & 1u)) >> 16;   // RNE to bf16
}

__device__ __forceinline__ float bf2f(unsigned short s) {
    return __uint_as_float(((unsigned int)s) << 16);
}

__device__ __forceinline__ int clamp_seg(int s) {
    return s < 0 ? 0 : (s > 511 ? 511 : s);
}

__global__ void conv_w_kernel(const float* __restrict__ W1, const float* __restrict__ W2,
                              unsigned short* __restrict__ W1b, unsigned short* __restrict__ W2b) {
    int i = blockIdx.x * 256 + threadIdx.x;           // 256 blocks x 256 = 65536
    W1b[i] = (unsigned short)f2bf(W1[i]);
    W2b[i] = (unsigned short)f2bf(W2[i]);
}

// ---------------- K1: h = relu(x @ W1^T + b1) -> bf16 ----------------
// Block = 64 rows x 256 cols. Wave w owns cols [64w, 64w+64).
// W1-slice lives in registers (Bf[4][8] = 128 VGPRs). No LDS, no barriers.
// MFMA 16x16x32 bf16: A[m=lane&15][k=quad*8+j]; B[k=quad*8+j][n=lane&15];
// C/D: col=lane&15, row=quad*4+reg.   (layouts verified passing in R1/R2)
__global__ __launch_bounds__(256, 2) void gemm1_kernel(
    const float* __restrict__ x,
    const unsigned short* __restrict__ W1b,
    const float* __restrict__ b1,
    unsigned short* __restrict__ hb)
{
    const int tid  = threadIdx.x;
    const int wave = tid >> 6;
    const int lane = tid & 63;
    const int r    = lane & 15;
    const int q    = lane >> 4;
    const int r0   = blockIdx.x * 64;
    const int cb   = wave * 64;

    // B-fragments: W1 rows [cb, cb+64), all K. 32 x b128 loads, L2-hot.
    bf16x8 Bf[4][8];
#pragma unroll
    for (int ct = 0; ct < 4; ++ct)
#pragma unroll
        for (int kk = 0; kk < 8; ++kk)
            Bf[ct][kk] = *(const bf16x8*)(W1b + (size_t)(cb + ct * 16 + r) * H + kk * 32 + q * 8);

    f32x4 acc[4][4];
#pragma unroll
    for (int mt = 0; mt < 4; ++mt)
#pragma unroll
        for (int ct = 0; ct < 4; ++ct) acc[mt][ct] = (f32x4){0.f, 0.f, 0.f, 0.f};

#pragma unroll
    for (int kk = 0; kk < 8; ++kk) {
#pragma unroll
        for (int mt = 0; mt < 4; ++mt) {
            const float* p = x + (size_t)(r0 + mt * 16 + r) * H + kk * 32 + q * 8;
            const float4 lo = *(const float4*)p;
            const float4 hi = *(const float4*)(p + 4);
            bf16x8 a;
            a[0] = (short)f2bf(lo.x); a[1] = (short)f2bf(lo.y);
            a[2] = (short)f2bf(lo.z); a[3] = (short)f2bf(lo.w);
            a[4] = (short)f2bf(hi.x); a[5] = (short)f2bf(hi.y);
            a[6] = (short)f2bf(hi.z); a[7] = (short)f2bf(hi.w);
#pragma unroll
            for (int ct = 0; ct < 4; ++ct)
                acc[mt][ct] = __builtin_amdgcn_mfma_f32_16x16x32_bf16(a, Bf[ct][kk], acc[mt][ct], 0, 0, 0);
        }
    }

#pragma unroll
    for (int ct = 0; ct < 4; ++ct) {
        const float bb = b1[cb + ct * 16 + r];
#pragma unroll
        for (int mt = 0; mt < 4; ++mt)
#pragma unroll
            for (int e = 0; e < 4; ++e) {
                float h = acc[mt][ct][e] + bb;
                h = h > 0.f ? h : 0.f;
                hb[(size_t)(r0 + mt * 16 + q * 4 + e) * H + cb + ct * 16 + r] = (unsigned short)f2bf(h);
            }
    }
}

// ---------------- K2: g = h * sigmoid(h @ W2^T + b2); segment max/sum ----------------
__global__ __launch_bounds__(256, 2) void gemm2_kernel(
    const unsigned short* __restrict__ hb,
    const int* __restrict__ batch,
    const unsigned short* __restrict__ W2b,
    const float* __restrict__ b2,
    float* __restrict__ out, int* __restrict__ counts)
{
    const int tid  = threadIdx.x;
    const int wave = tid >> 6;
    const int lane = tid & 63;
    const int r    = lane & 15;
    const int q    = lane >> 4;
    const int r0   = blockIdx.x * 64;
    const int cb   = wave * 64;

    bf16x8 Bf[4][8];
#pragma unroll
    for (int ct = 0; ct < 4; ++ct)
#pragma unroll
        for (int kk = 0; kk < 8; ++kk)
            Bf[ct][kk] = *(const bf16x8*)(W2b + (size_t)(cb + ct * 16 + r) * H + kk * 32 + q * 8);

    f32x4 acc[4][4];
#pragma unroll
    for (int mt = 0; mt < 4; ++mt)
#pragma unroll
        for (int ct = 0; ct < 4; ++ct) acc[mt][ct] = (f32x4){0.f, 0.f, 0.f, 0.f};

#pragma unroll
    for (int kk = 0; kk < 8; ++kk) {
#pragma unroll
        for (int mt = 0; mt < 4; ++mt) {
            const bf16x8 a = *(const bf16x8*)(hb + (size_t)(r0 + mt * 16 + r) * H + kk * 32 + q * 8);
#pragma unroll
            for (int ct = 0; ct < 4; ++ct)
                acc[mt][ct] = __builtin_amdgcn_mfma_f32_16x16x32_bf16(a, Bf[ct][kk], acc[mt][ct], 0, 0, 0);
        }
    }

    // gate: g = h_bf16 * sigmoid(acc + b2)  (g >= 0 since h >= 0)
#pragma unroll
    for (int ct = 0; ct < 4; ++ct) {
        const float bb = b2[cb + ct * 16 + r];
#pragma unroll
        for (int mt = 0; mt < 4; ++mt)
#pragma unroll
            for (int e = 0; e < 4; ++e) {
                const float t   = acc[mt][ct][e] + bb;
                const float att = 1.f / (1.f + __expf(-t));
                const float hv  = bf2f(hb[(size_t)(r0 + mt * 16 + q * 4 + e) * H + cb + ct * 16 + r]);
                acc[mt][ct][e] = hv * att;
            }
    }

    // ---- segment reduction (batch sorted) ----
    if (batch[r0] == batch[r0 + 63]) {
        // whole block in one segment (~84% of blocks): combine all 16 rows/lane first
        const int sg = clamp_seg(batch[r0]);
#pragma unroll
        for (int ct = 0; ct < 4; ++ct) {
            float s = 0.f, m = 0.f;
#pragma unroll
            for (int mt = 0; mt < 4; ++mt)
#pragma unroll
                for (int e = 0; e < 4; ++e) {
                    const float v = acc[mt][ct][e];
                    s += v;
                    m = fmaxf(m, v);
                }
            s += __shfl_xor(s, 16, 64);
            s += __shfl_xor(s, 32, 64);
            m = fmaxf(m, __shfl_xor(m, 16, 64));
            m = fmaxf(m, __shfl_xor(m, 32, 64));
            if (q == 0) {
                const int col = cb + ct * 16 + r;
                atomicAdd(&out[(size_t)sg * 512 + 256 + col], s);
                atomicMax((unsigned int*)&out[(size_t)sg * 512 + col], __float_as_uint(m));
            }
        }
    } else {
#pragma unroll
        for (int mt = 0; mt < 4; ++mt) {
            const int rm = r0 + mt * 16;
            const int s0 = batch[rm], s1 = batch[rm + 15];
            if (s0 == s1) {
                const int sg = clamp_seg(s0);
#pragma unroll
                for (int ct = 0; ct < 4; ++ct) {
                    const f32x4 v = acc[mt][ct];
                    float s = v[0] + v[1] + v[2] + v[3];
                    float m = fmaxf(fmaxf(v[0], v[1]), fmaxf(v[2], v[3]));
                    s += __shfl_xor(s, 16, 64);
                    s += __shfl_xor(s, 32, 64);
                    m = fmaxf(m, __shfl_xor(m, 16, 64));
                    m = fmaxf(m, __shfl_xor(m, 32, 64));
                    if (q == 0) {
                        const int col = cb + ct * 16 + r;
                        atomicAdd(&out[(size_t)sg * 512 + 256 + col], s);
                        atomicMax((unsigned int*)&out[(size_t)sg * 512 + col], __float_as_uint(m));
                    }
                }
            } else {
                // true segment boundary inside this 16-row group (rare)
#pragma unroll
                for (int e = 0; e < 4; ++e) {
                    const int sg = clamp_seg(batch[rm + q * 4 + e]);
#pragma unroll
                    for (int ct = 0; ct < 4; ++ct) {
                        const int col = cb + ct * 16 + r;
                        const float v = acc[mt][ct][e];
                        atomicAdd(&out[(size_t)sg * 512 + 256 + col], v);
                        atomicMax((unsigned int*)&out[(size_t)sg * 512 + col], __float_as_uint(v));
                    }
                }
            }
        }
    }

    if (tid < 64) {
        const int sg = clamp_seg(batch[r0 + tid]);
        atomicAdd(&counts[sg], 1);
    }
}

__global__ void finalize_kernel(float* __restrict__ out, const int* __restrict__ counts) {
    const int b = blockIdx.x;
    const int c = threadIdx.x;
    const int cnt = counts[b];
    float s = out[(size_t)b * 512 + 256 + c];
    out[(size_t)b * 512 + 256 + c] = cnt > 0 ? s / (float)cnt : 0.0f;
}

extern "C" void kernel_launch(void* const* d_in, const int* in_sizes, int n_in,
                              void* d_out, int out_size, void* d_ws, size_t ws_size,
                              hipStream_t stream) {
    const float* x     = (const float*)d_in[0];
    const int*   batch = (const int*)d_in[1];
    const float* W1    = (const float*)d_in[2];
    const float* b1    = (const float*)d_in[3];
    const float* W2    = (const float*)d_in[4];
    const float* b2    = (const float*)d_in[5];
    float* out = (float*)d_out;

    const int Nrows  = in_sizes[0] / H;   // 200000
    const int blocks = Nrows / 64;        // 3125 (exact)

    // ws layout: hb [200000*256 bf16 = 102.4 MB] | W1b | W2b | counts
    unsigned short* hb     = (unsigned short*)d_ws;
    unsigned short* W1b    = hb + (size_t)Nrows * H;
    unsigned short* W2b    = W1b + 65536;
    int*            counts = (int*)(W2b + 65536);

    hipMemsetAsync(d_out, 0, (size_t)out_size * sizeof(float), stream);
    hipMemsetAsync(counts, 0, 512 * sizeof(int), stream);
    conv_w_kernel<<<256, 256, 0, stream>>>(W1, W2, W1b, W2b);
    gemm1_kernel<<<blocks, 256, 0, stream>>>(x, W1b, b1, hb);
    gemm2_kernel<<<blocks, 256, 0, stream>>>(hb, batch, W2b, b2, out, counts);
    finalize_kernel<<<512, 256, 0, stream>>>(out, counts);
}

// Round 4
// 674.060 us; speedup vs baseline: 1.2329x; 1.2329x over previous
//
#include <hip/hip_runtime.h>

#define H 256

typedef short bf16x8 __attribute__((ext_vector_type(8)));
typedef float f32x4  __attribute__((ext_vector_type(4)));

__device__ __forceinline__ unsigned int f2bf(float f) {
    unsigned int u = __float_as_uint(f);
    return (u + 0x7fffu + ((u >> 16) & 1u)) >> 16;   // RNE to bf16
}

__device__ __forceinline__ float bf2f(unsigned short s) {
    return __uint_as_float(((unsigned int)s) << 16);
}

__device__ __forceinline__ int clamp_seg(int s) {
    return s < 0 ? 0 : (s > 511 ? 511 : s);
}

__global__ void conv_w_kernel(const float* __restrict__ W1, const float* __restrict__ W2,
                              unsigned short* __restrict__ W1b, unsigned short* __restrict__ W2b) {
    int i = blockIdx.x * 256 + threadIdx.x;           // 256 blocks x 256 = 65536
    W1b[i] = (unsigned short)f2bf(W1[i]);
    W2b[i] = (unsigned short)f2bf(W2[i]);
}

// Fused: h = relu(x@W1^T+b1); g = h*sigmoid(h@W2^T+b2); segment max/sum.
// Block = 64 rows; wave w owns output cols [64w, 64w+64).
// MFMA 16x16x32 bf16: A[m=lane&15][k=quad*8+j]; B[k=quad*8+j][n=lane&15];
// C/D: col=lane&15, row=quad*4+reg.  (verified passing R1-R3)
__global__ __launch_bounds__(256, 2) void fused_main(
    const float* __restrict__ x, const int* __restrict__ batch,
    const unsigned short* __restrict__ W1b, const float* __restrict__ b1,
    const unsigned short* __restrict__ W2b, const float* __restrict__ b2,
    float* __restrict__ out, int* __restrict__ counts)
{
    __shared__ __align__(16) unsigned short hlds[64][264];  // 33792 B -> 2 blocks/CU

    const int tid  = threadIdx.x;
    const int wave = tid >> 6;
    const int lane = tid & 63;
    const int r    = lane & 15;
    const int q    = lane >> 4;
    const int r0   = blockIdx.x * 64;
    const int cb   = wave * 64;

    // ---- segment bookkeeping (early) ----
    const int  b_lo   = batch[r0];
    const int  b_hi   = batch[r0 + 63];
    const bool blkuni = (b_lo == b_hi);
    const int  sgu    = clamp_seg(b_lo);
    int  sgm[4];
    bool unim[4];
#pragma unroll
    for (int mt = 0; mt < 4; ++mt) {
        const int s0 = batch[r0 + mt * 16];
        const int s1 = batch[r0 + mt * 16 + 15];
        unim[mt] = (s0 == s1);
        sgm[mt]  = clamp_seg(s0);
    }

    // ---- 1. preload x tile -> a1[mt][kk] (128 VGPRs), deep MLP ----
    bf16x8 a1[4][8];
#pragma unroll
    for (int mt = 0; mt < 4; ++mt) {
        const float* xrow = x + (size_t)(r0 + mt * 16 + r) * H;
#pragma unroll
        for (int kk = 0; kk < 8; ++kk) {
            const float4 lo = *(const float4*)(xrow + kk * 32 + q * 8);
            const float4 hi = *(const float4*)(xrow + kk * 32 + q * 8 + 4);
            bf16x8 a;
            a[0] = (short)f2bf(lo.x); a[1] = (short)f2bf(lo.y);
            a[2] = (short)f2bf(lo.z); a[3] = (short)f2bf(lo.w);
            a[4] = (short)f2bf(hi.x); a[5] = (short)f2bf(hi.y);
            a[6] = (short)f2bf(hi.z); a[7] = (short)f2bf(hi.w);
            a1[mt][kk] = a;
        }
    }

    // ---- 2. GEMM1 per 16-col chunk (live set: a1 + Bf[8] + acc[4]) ----
#pragma unroll
    for (int ct = 0; ct < 4; ++ct) {
        const int wrow = cb + ct * 16 + r;           // W1 row = output col
        bf16x8 Bf[8];
#pragma unroll
        for (int kk = 0; kk < 8; ++kk)
            Bf[kk] = *(const bf16x8*)(W1b + (size_t)wrow * H + kk * 32 + q * 8);

        f32x4 acc[4];
#pragma unroll
        for (int mt = 0; mt < 4; ++mt) acc[mt] = (f32x4){0.f, 0.f, 0.f, 0.f};
#pragma unroll
        for (int kk = 0; kk < 8; ++kk)
#pragma unroll
            for (int mt = 0; mt < 4; ++mt)
                acc[mt] = __builtin_amdgcn_mfma_f32_16x16x32_bf16(a1[mt][kk], Bf[kk], acc[mt], 0, 0, 0);

        const float bb = b1[wrow];
#pragma unroll
        for (int mt = 0; mt < 4; ++mt)
#pragma unroll
            for (int e = 0; e < 4; ++e) {
                float h = acc[mt][e] + bb;
                h = h > 0.f ? h : 0.f;
                hlds[mt * 16 + q * 4 + e][cb + ct * 16 + r] = (unsigned short)f2bf(h);
            }
    }
    __syncthreads();

    // ---- 3. a2 fragments from hlds (conflict-free b128, pad 264) ----
    bf16x8 a2[4][8];
#pragma unroll
    for (int mt = 0; mt < 4; ++mt)
#pragma unroll
        for (int kk = 0; kk < 8; ++kk)
            a2[mt][kk] = *(const bf16x8*)&hlds[mt * 16 + r][kk * 32 + q * 8];

    // ---- 4. GEMM2 per chunk + gate + segment reduction ----
#pragma unroll
    for (int ct = 0; ct < 4; ++ct) {
        const int wrow = cb + ct * 16 + r;
        bf16x8 Bf[8];
#pragma unroll
        for (int kk = 0; kk < 8; ++kk)
            Bf[kk] = *(const bf16x8*)(W2b + (size_t)wrow * H + kk * 32 + q * 8);

        f32x4 acc[4];
#pragma unroll
        for (int mt = 0; mt < 4; ++mt) acc[mt] = (f32x4){0.f, 0.f, 0.f, 0.f};
#pragma unroll
        for (int kk = 0; kk < 8; ++kk)
#pragma unroll
            for (int mt = 0; mt < 4; ++mt)
                acc[mt] = __builtin_amdgcn_mfma_f32_16x16x32_bf16(a2[mt][kk], Bf[kk], acc[mt], 0, 0, 0);

        const float bb  = b2[wrow];
        const int   col = cb + ct * 16 + r;
#pragma unroll
        for (int mt = 0; mt < 4; ++mt)
#pragma unroll
            for (int e = 0; e < 4; ++e) {
                const float t   = acc[mt][e] + bb;
                const float att = 1.f / (1.f + __expf(-t));
                const float hv  = bf2f(hlds[mt * 16 + q * 4 + e][col]);
                acc[mt][e] = hv * att;   // g >= 0
            }

        if (blkuni) {
            float s = 0.f, m = 0.f;
#pragma unroll
            for (int mt = 0; mt < 4; ++mt)
#pragma unroll
                for (int e = 0; e < 4; ++e) {
                    const float v = acc[mt][e];
                    s += v;
                    m = fmaxf(m, v);
                }
            s += __shfl_xor(s, 16, 64);
            s += __shfl_xor(s, 32, 64);
            m = fmaxf(m, __shfl_xor(m, 16, 64));
            m = fmaxf(m, __shfl_xor(m, 32, 64));
            if (q == 0) {
                atomicAdd(&out[(size_t)sgu * 512 + 256 + col], s);
                atomicMax((unsigned int*)&out[(size_t)sgu * 512 + col], __float_as_uint(m));
            }
        } else {
#pragma unroll
            for (int mt = 0; mt < 4; ++mt) {
                if (unim[mt]) {
                    const f32x4 v = acc[mt];
                    float s = v[0] + v[1] + v[2] + v[3];
                    float m = fmaxf(fmaxf(v[0], v[1]), fmaxf(v[2], v[3]));
                    s += __shfl_xor(s, 16, 64);
                    s += __shfl_xor(s, 32, 64);
                    m = fmaxf(m, __shfl_xor(m, 16, 64));
                    m = fmaxf(m, __shfl_xor(m, 32, 64));
                    if (q == 0) {
                        atomicAdd(&out[(size_t)sgm[mt] * 512 + 256 + col], s);
                        atomicMax((unsigned int*)&out[(size_t)sgm[mt] * 512 + col], __float_as_uint(m));
                    }
                } else {
#pragma unroll
                    for (int e = 0; e < 4; ++e) {
                        const int sg = clamp_seg(batch[r0 + mt * 16 + q * 4 + e]);
                        const float v = acc[mt][e];
                        atomicAdd(&out[(size_t)sg * 512 + 256 + col], v);
                        atomicMax((unsigned int*)&out[(size_t)sg * 512 + col], __float_as_uint(v));
                    }
                }
            }
        }
    }

    if (tid < 64) {
        const int sg = clamp_seg(batch[r0 + tid]);
        atomicAdd(&counts[sg], 1);
    }
}

__global__ void finalize_kernel(float* __restrict__ out, const int* __restrict__ counts) {
    const int b = blockIdx.x;
    const int c = threadIdx.x;
    const int cnt = counts[b];
    float s = out[(size_t)b * 512 + 256 + c];
    out[(size_t)b * 512 + 256 + c] = cnt > 0 ? s / (float)cnt : 0.0f;
}

extern "C" void kernel_launch(void* const* d_in, const int* in_sizes, int n_in,
                              void* d_out, int out_size, void* d_ws, size_t ws_size,
                              hipStream_t stream) {
    const float* x     = (const float*)d_in[0];
    const int*   batch = (const int*)d_in[1];
    const float* W1    = (const float*)d_in[2];
    const float* b1    = (const float*)d_in[3];
    const float* W2    = (const float*)d_in[4];
    const float* b2    = (const float*)d_in[5];
    float* out = (float*)d_out;

    unsigned short* W1b    = (unsigned short*)d_ws;
    unsigned short* W2b    = W1b + 65536;
    int*            counts = (int*)(W2b + 65536);

    const int Nrows  = in_sizes[0] / H;   // 200000
    const int blocks = Nrows / 64;        // 3125 (exact)

    hipMemsetAsync(d_out, 0, (size_t)out_size * sizeof(float), stream);
    hipMemsetAsync(counts, 0, 512 * sizeof(int), stream);
    conv_w_kernel<<<256, 256, 0, stream>>>(W1, W2, W1b, W2b);
    fused_main<<<blocks, 256, 0, stream>>>(x, batch, W1b, b1, W2b, b2, out, counts);
    finalize_kernel<<<512, 256, 0, stream>>>(out, counts);
}